// Round 11
// baseline (381.899 us; speedup 1.0000x reference)
//
#include <hip/hip_runtime.h>

// ---------------------------------------------------------------------------
// GCN 2-layer forward on MI355X.
//   h1s = dinv * (X @ W1)            (global_load_lds MFMA GEMM, dbuf prefetch)
//   h2  = relu(dinv * sum h1s + b1)  (CSR gather, 8-deep pipelined, bf16)
//   t2s = dinv * (h2 @ W2)           (bf16 MFMA GEMM + norm epilogue)
//   out = dinv * sum t2s + b2        (CSR gather, fp32 out)
// R11: gemm1 v5 — double-buffered LDS. R10's single-buffer 2-barrier loop
// exposed full HBM latency every K-step (MfmaUtil 7.7%, zero stage/compute
// overlap). Now: STAGE(next)->compute(cur)->barrier, one barrier per iter;
// prefetch overlaps the whole compute phase (T3-minimum 2-phase recipe).
// ---------------------------------------------------------------------------

typedef __bf16 bf16x8 __attribute__((ext_vector_type(8)));
typedef __bf16 bf16x4 __attribute__((ext_vector_type(4)));
typedef float  f32x4  __attribute__((ext_vector_type(4)));

#define N_NODES  50000
#define N_PAD    50048   // 782 * 64
#define ZERO_ROW 50000   // first pad row: always all-zero in h1s/h2/t2s
#define F_IN     512
#define F_HID    256
#define F_OUT    64
#define SCAN_B   196     // ceil(50000 / 256)

#define GLOAD_LDS16(gp, lp) __builtin_amdgcn_global_load_lds(               \
    (const __attribute__((address_space(1))) void*)(gp),                    \
    (__attribute__((address_space(3))) void*)(lp), 16, 0, 0)

// ---------------------------------------------------------------------------
// W [K][N] f32 -> WT [N][K] bf16
__global__ __launch_bounds__(256) void convw_kernel(
    const float* __restrict__ W, __bf16* __restrict__ WT, int K, int N)
{
    int i = blockIdx.x * blockDim.x + threadIdx.x;
    if (i >= N * K) return;
    int n = i / K, k = i - n * K;
    WT[i] = (__bf16)W[(size_t)k * N + n];
}

// srcidx init: every slot points at the zero row (pad slots keep this)
__global__ __launch_bounds__(256) void initsrc_kernel(
    int* __restrict__ srcidx, int n4)
{
    int i = blockIdx.x * blockDim.x + threadIdx.x;
    if (i < n4) {
        int4 v = make_int4(ZERO_ROW, ZERO_ROW, ZERO_ROW, ZERO_ROW);
        *(int4*)(srcidx + i * 4) = v;
    }
}

// ---------------------------------------------------------------------------
// CSR build: histogram (4 edges/thread), scan of %8-padded caps, sort fill
__global__ __launch_bounds__(256) void count_kernel(
    const int* __restrict__ col, int E, int Nn, int* __restrict__ cnt)
{
    int e0 = (blockIdx.x * blockDim.x + threadIdx.x) * 4;
    if (e0 >= E) return;                 // E % 4 == 0
    int4 cc = *(const int4*)(col + e0);
    if ((unsigned)cc.x < (unsigned)Nn) atomicAdd(&cnt[cc.x], 1);
    if ((unsigned)cc.y < (unsigned)Nn) atomicAdd(&cnt[cc.y], 1);
    if ((unsigned)cc.z < (unsigned)Nn) atomicAdd(&cnt[cc.z], 1);
    if ((unsigned)cc.w < (unsigned)Nn) atomicAdd(&cnt[cc.w], 1);
}

__global__ __launch_bounds__(256) void scan_partial_kernel(
    const int* __restrict__ cnt, int* __restrict__ bsum, int N)
{
    __shared__ int s[256];
    const int t = threadIdx.x;
    const int i = blockIdx.x * 256 + t;
    int v = (i < N) ? ((cnt[i] + 1 + 7) & ~7) : 0;
    s[t] = v;
    __syncthreads();
    #pragma unroll
    for (int off = 128; off > 0; off >>= 1) {
        if (t < off) s[t] += s[t + off];
        __syncthreads();
    }
    if (t == 0) bsum[blockIdx.x] = s[0];
}

__global__ __launch_bounds__(256) void scan_bsum_kernel(
    const int* __restrict__ bsum, int* __restrict__ bofs,
    int* __restrict__ offs, int N, int PB)
{
    __shared__ int s[256];
    const int t = threadIdx.x;
    int v = (t < PB) ? bsum[t] : 0;
    s[t] = v;
    __syncthreads();
    #pragma unroll
    for (int off = 1; off < 256; off <<= 1) {
        int u = (t >= off) ? s[t - off] : 0;
        __syncthreads();
        s[t] += u;
        __syncthreads();
    }
    if (t < PB) bofs[t] = s[t] - v;
    if (t == 255) offs[N] = s[255];
}

__global__ __launch_bounds__(256) void scan_fill_kernel(
    const int* __restrict__ cnt, const int* __restrict__ bofs,
    int* __restrict__ offs, float* __restrict__ dinv, int N)
{
    __shared__ int s[256];
    const int t = threadIdx.x;
    const int i = blockIdx.x * 256 + t;
    int c   = (i < N) ? cnt[i] + 1 : 0;
    int cap = (c + 7) & ~7;
    s[t] = cap;
    __syncthreads();
    #pragma unroll
    for (int off = 1; off < 256; off <<= 1) {
        int u = (t >= off) ? s[t - off] : 0;
        __syncthreads();
        s[t] += u;
        __syncthreads();
    }
    if (i < N) {
        offs[i] = bofs[blockIdx.x] + s[t] - cap;
        dinv[i] = rsqrtf((float)c);
    }
}

__global__ __launch_bounds__(256) void fill_kernel(
    const int* __restrict__ row, const int* __restrict__ col,
    int E, int Nn, const int* __restrict__ offs,
    int* __restrict__ fill, int* __restrict__ srcidx)
{
    int e0 = (blockIdx.x * blockDim.x + threadIdx.x) * 4;
    int total = E + Nn;
    if (e0 >= total) return;
    int rr[4], cc[4];
    #pragma unroll
    for (int j = 0; j < 4; ++j) {
        int e = e0 + j;
        if (e < E)      { cc[j] = col[e]; rr[j] = row[e]; }
        else            { int i = e - E; cc[j] = (i < Nn) ? i : -1; rr[j] = cc[j]; }
    }
    #pragma unroll
    for (int j = 0; j < 4; ++j) {
        int c = cc[j], r = rr[j];
        if ((unsigned)c < (unsigned)Nn && (unsigned)r < (unsigned)Nn) {
            int p = offs[c] + atomicAdd(&fill[c], 1);
            srcidx[p] = r;
        }
    }
}

// ---------------------------------------------------------------------------
// GEMM1 v5: C[50048][256] = dinv[r] * (cvt_bf16(Xf32)[50048][512] @ W1T^T)
// BM=64, BN=256, BK=32, 4 waves (2x2), 16x16x32 MFMA.
// Double-buffered LDS + global_load_lds width=16: per iter, STAGE tile k+1
// into buf^1, compute tile k from buf, one __syncthreads() (drains prefetch
// after it overlapped the compute phase). No WAR: buf^1's readers finished
// before the previous barrier.
// Per-buffer layout: A fp32 [64][32] @0 (8KB), B bf16 [256][32] @8192 (16KB).
// XOR swizzle both sides: A chunk16 c'=c^(row&7); B chunk16 c'=c^((row>>1)&3).
__global__ __launch_bounds__(256, 3) void gemm1_kernel(
    const float* __restrict__ A, const __bf16* __restrict__ BT,
    const float* __restrict__ dinv, __bf16* __restrict__ C)
{
    __shared__ __align__(16) unsigned char lds[2][24576];

    const int tid  = threadIdx.x;
    const int lane = tid & 63;
    const int wv   = tid >> 6;
    const int wm = wv >> 1, wn = wv & 1;
    const int bm = blockIdx.x * 64;
    const int lr = lane & 15, kg = lane >> 4;

    // staging geometry (per-wave segments, lane l covers 16B)
    const int cA = (lane & 7) ^ (lane >> 3);          // A: row&7 == l>>3
    const int cB = (lane & 3) ^ ((lane >> 3) & 3);    // B: (row>>1)&3

    const float* gA[2]; int aoff[2];
    #pragma unroll
    for (int q = 0; q < 2; ++q) {
        int s   = wv * 2 + q;
        int row = s * 8 + (lane >> 3);
        int gr  = bm + row;
        if (gr >= N_NODES) gr = 0;       // clamp; pad C rows zeroed by dinv=0
        gA[q]   = A + (size_t)gr * F_IN + cA * 4;
        aoff[q] = s * 1024;
    }
    const __bf16* gB[4]; int boff[4];
    #pragma unroll
    for (int q = 0; q < 4; ++q) {
        int s   = wv * 4 + q;
        int row = s * 16 + (lane >> 2);
        gB[q]   = BT + (size_t)row * F_IN + cB * 8;
        boff[q] = 8192 + s * 1024;
    }

#define STAGE(b, kc) {                                                      \
        _Pragma("unroll")                                                   \
        for (int q = 0; q < 2; ++q)                                         \
            GLOAD_LDS16(gA[q] + (kc) * 32, &lds[b][aoff[q]]);               \
        _Pragma("unroll")                                                   \
        for (int q = 0; q < 4; ++q)                                         \
            GLOAD_LDS16(gB[q] + (kc) * 32, &lds[b][boff[q]]); }

    f32x4 acc[2][8] = {};

    STAGE(0, 0)
    __syncthreads();

    #pragma unroll
    for (int kc = 0; kc < 16; ++kc) {
        const int cur = kc & 1;
        if (kc + 1 < 16) STAGE(cur ^ 1, kc + 1)

        const unsigned char* lb = lds[cur];
        bf16x8 af[2];
        #pragma unroll
        for (int m = 0; m < 2; ++m) {
            int ar = wm * 32 + m * 16 + lr;
            int h0 = ((kg << 1)    ) ^ (ar & 7);
            int h1 = ((kg << 1) | 1) ^ (ar & 7);
            float4 x0 = *(const float4*)(lb + (ar << 7) + (h0 << 4));
            float4 x1 = *(const float4*)(lb + (ar << 7) + (h1 << 4));
            af[m][0]=(__bf16)x0.x; af[m][1]=(__bf16)x0.y;
            af[m][2]=(__bf16)x0.z; af[m][3]=(__bf16)x0.w;
            af[m][4]=(__bf16)x1.x; af[m][5]=(__bf16)x1.y;
            af[m][6]=(__bf16)x1.z; af[m][7]=(__bf16)x1.w;
        }
        #pragma unroll
        for (int n = 0; n < 8; ++n) {
            int br = wn * 128 + n * 16 + lr;
            int ph = kg ^ ((br >> 1) & 3);
            bf16x8 bf = *(const bf16x8*)(lb + 8192 + (br << 6) + (ph << 4));
            #pragma unroll
            for (int m = 0; m < 2; ++m)
                acc[m][n] = __builtin_amdgcn_mfma_f32_16x16x32_bf16(
                    af[m], bf, acc[m][n], 0, 0, 0);
        }
        __syncthreads();   // prefetch (overlapped with the MFMAs above) lands
    }
#undef STAGE

    const int crow0 = bm + wm * 32 + kg * 4;
    const int ccol0 = wn * 128 + lr;
    #pragma unroll
    for (int m = 0; m < 2; ++m) {
        #pragma unroll
        for (int j = 0; j < 4; ++j) {
            int r = crow0 + m * 16 + j;
            float dv = (r < N_NODES) ? dinv[r] : 0.f;
            #pragma unroll
            for (int n = 0; n < 8; ++n)
                C[(size_t)r * F_HID + (ccol0 + n * 16)] = (__bf16)(dv * acc[m][n][j]);
        }
    }
}

// ---------------------------------------------------------------------------
// GEMM2: C[Mpad][N] = dinv[r] * (A[Mpad][K] @ BT[N][K]^T)
template<int WGM, int WGN, int FM, int FN>
__global__ __launch_bounds__(256) void gemm_kernel(
    const __bf16* __restrict__ A, const __bf16* __restrict__ BT,
    const float* __restrict__ dinv, __bf16* __restrict__ C, int K, int N)
{
    constexpr int BM = WGM * FM * 16;
    constexpr int BN = WGN * FN * 16;
    constexpr int BK = 32;
    constexpr int LDT = BK + 8;
    __shared__ __bf16 As[BM * LDT];
    __shared__ __bf16 Bs[BN * LDT];

    const int tid  = threadIdx.x;
    const int lane = tid & 63;
    const int wid  = tid >> 6;
    const int wm = wid / WGN, wn = wid % WGN;
    const int bm = blockIdx.x * BM;
    const int bn = blockIdx.y * BN;
    const int lr = lane & 15, kg = lane >> 4;

    const int arow = tid >> 2;
    const int achk = (tid & 3) * 8;

    f32x4 acc[FM][FN] = {};

    for (int k0 = 0; k0 < K; k0 += BK) {
        bf16x8 ra[BM / 64], rb[BN / 64];
        #pragma unroll
        for (int p = 0; p < BM / 64; ++p)
            ra[p] = *(const bf16x8*)(A + (size_t)(bm + p * 64 + arow) * K + k0 + achk);
        #pragma unroll
        for (int p = 0; p < BN / 64; ++p)
            rb[p] = *(const bf16x8*)(BT + (size_t)(bn + p * 64 + arow) * K + k0 + achk);
        __syncthreads();
        #pragma unroll
        for (int p = 0; p < BM / 64; ++p)
            *(bf16x8*)(As + (p * 64 + arow) * LDT + achk) = ra[p];
        #pragma unroll
        for (int p = 0; p < BN / 64; ++p)
            *(bf16x8*)(Bs + (p * 64 + arow) * LDT + achk) = rb[p];
        __syncthreads();

        bf16x8 af[FM], bfv[FN];
        #pragma unroll
        for (int m = 0; m < FM; ++m)
            af[m] = *(const bf16x8*)(As + (wm * FM * 16 + m * 16 + lr) * LDT + kg * 8);
        #pragma unroll
        for (int n = 0; n < FN; ++n)
            bfv[n] = *(const bf16x8*)(Bs + (wn * FN * 16 + n * 16 + lr) * LDT + kg * 8);
        #pragma unroll
        for (int m = 0; m < FM; ++m)
            #pragma unroll
            for (int n = 0; n < FN; ++n)
                acc[m][n] = __builtin_amdgcn_mfma_f32_16x16x32_bf16(
                    af[m], bfv[n], acc[m][n], 0, 0, 0);
    }

    const int crow0 = bm + wm * FM * 16 + kg * 4;
    const int ccol0 = bn + wn * FN * 16 + lr;
    #pragma unroll
    for (int m = 0; m < FM; ++m) {
        #pragma unroll
        for (int j = 0; j < 4; ++j) {
            int r = crow0 + m * 16 + j;
            float dv = (r < N_NODES) ? dinv[r] : 0.f;
            #pragma unroll
            for (int n = 0; n < FN; ++n)
                C[(size_t)r * N + (ccol0 + n * 16)] = (__bf16)(dv * acc[m][n][j]);
        }
    }
}

// ---------------------------------------------------------------------------
// CSR aggregation, 8-deep: out[n][f] = dinv[n]*sum_e Hs[src[e]][f] + bias[f]
template<int F, int FP, bool RELU, bool BF16OUT>
__global__ __launch_bounds__(256) void agg_kernel(
    const __bf16* __restrict__ H,
    const int* __restrict__ offs, const int* __restrict__ srcidx,
    const float* __restrict__ dinv, const float* __restrict__ bias,
    __bf16* __restrict__ outb, float* __restrict__ outf,
    int Nn, int Mpad)
{
    const int lane = threadIdx.x & 63;
    const int node = blockIdx.x * 4 + (threadIdx.x >> 6);
    if (node >= Mpad) return;
    if (node >= Nn) {
        if (BF16OUT) {
            #pragma unroll
            for (int j = 0; j < FP; ++j)
                outb[(size_t)node * F + lane * FP + j] = (__bf16)0.f;
        }
        return;
    }
    const int e0 = offs[node], e1 = offs[node + 1];   // both %8 == 0
    const float dv = dinv[node];
    float acc[FP] = {};
    for (int e = e0; e < e1; e += 8) {
        int4 sa = *(const int4*)(srcidx + e);
        int4 sb = *(const int4*)(srcidx + e + 4);
        if constexpr (FP == 4) {
            bf16x4 v0 = *(const bf16x4*)(H + (size_t)sa.x * F + lane * 4);
            bf16x4 v1 = *(const bf16x4*)(H + (size_t)sa.y * F + lane * 4);
            bf16x4 v2 = *(const bf16x4*)(H + (size_t)sa.z * F + lane * 4);
            bf16x4 v3 = *(const bf16x4*)(H + (size_t)sa.w * F + lane * 4);
            bf16x4 v4 = *(const bf16x4*)(H + (size_t)sb.x * F + lane * 4);
            bf16x4 v5 = *(const bf16x4*)(H + (size_t)sb.y * F + lane * 4);
            bf16x4 v6 = *(const bf16x4*)(H + (size_t)sb.z * F + lane * 4);
            bf16x4 v7 = *(const bf16x4*)(H + (size_t)sb.w * F + lane * 4);
            #pragma unroll
            for (int j = 0; j < 4; ++j)
                acc[j] += ((float)v0[j] + (float)v1[j] + (float)v2[j] + (float)v3[j])
                        + ((float)v4[j] + (float)v5[j] + (float)v6[j] + (float)v7[j]);
        } else {
            __bf16 v0 = H[(size_t)sa.x * F + lane];
            __bf16 v1 = H[(size_t)sa.y * F + lane];
            __bf16 v2 = H[(size_t)sa.z * F + lane];
            __bf16 v3 = H[(size_t)sa.w * F + lane];
            __bf16 v4 = H[(size_t)sb.x * F + lane];
            __bf16 v5 = H[(size_t)sb.y * F + lane];
            __bf16 v6 = H[(size_t)sb.z * F + lane];
            __bf16 v7 = H[(size_t)sb.w * F + lane];
            acc[0] += ((float)v0 + (float)v1 + (float)v2 + (float)v3)
                    + ((float)v4 + (float)v5 + (float)v6 + (float)v7);
        }
    }
    if constexpr (BF16OUT) {
        bf16x4 ov;
        #pragma unroll
        for (int j = 0; j < FP; ++j) {
            float r = dv * acc[j] + bias[lane * FP + j];
            if (RELU) r = fmaxf(r, 0.f);
            if constexpr (FP == 4) ov[j] = (__bf16)r;
            else outb[(size_t)node * F + lane] = (__bf16)r;
        }
        if constexpr (FP == 4)
            *(bf16x4*)(outb + (size_t)node * F + lane * 4) = ov;
    } else {
        #pragma unroll
        for (int j = 0; j < FP; ++j) {
            float r = dv * acc[j] + bias[lane * FP + j];
            if (RELU) r = fmaxf(r, 0.f);
            outf[(size_t)node * F + lane * FP + j] = r;
        }
    }
}

// ---------------------------------------------------------------------------
extern "C" void kernel_launch(void* const* d_in, const int* in_sizes, int n_in,
                              void* d_out, int out_size, void* d_ws, size_t ws_size,
                              hipStream_t stream)
{
    const float* x   = (const float*)d_in[0];
    const int*   ei  = (const int*)d_in[1];
    const float* W1  = (const float*)d_in[2];
    const float* b1  = (const float*)d_in[3];
    const float* W2  = (const float*)d_in[4];
    const float* b2  = (const float*)d_in[5];
    const int E  = in_sizes[1] / 2;
    const int Nn = N_NODES;
    const int E2P = E + 8 * Nn;            // %8-padded CSR capacity upper bound
    const int* rowp = ei;
    const int* colp = ei + E;

    char* w = (char*)d_ws;
    auto alloc = [&](size_t bytes) {
        char* p = w; w += (bytes + 255) & ~(size_t)255; return p;
    };
    __bf16* h1   = (__bf16*)alloc((size_t)N_PAD * F_HID * 2);  // reused as t2
    __bf16* h2   = (__bf16*)alloc((size_t)N_PAD * F_HID * 2);
    __bf16* w1t  = (__bf16*)alloc((size_t)F_HID * F_IN  * 2);
    __bf16* w2t  = (__bf16*)alloc((size_t)F_OUT * F_HID * 2);
    int*    cnt  = (int*)  alloc((size_t)Nn * 4);
    int*    fil  = (int*)  alloc((size_t)Nn * 4);
    int*    offs = (int*)  alloc((size_t)(Nn + 1) * 4);
    float*  dinv = (float*)alloc((size_t)Nn * 4);
    int*    bsum = (int*)  alloc((size_t)SCAN_B * 4);
    int*    bofs = (int*)  alloc((size_t)SCAN_B * 4);
    int*    srcx = (int*)  alloc((size_t)E2P * 4);
    __bf16* t2 = h1;    // h1 dead after agg1

    hipMemsetAsync(cnt, 0, (size_t)Nn * 4, stream);
    hipMemsetAsync(fil, 0, (size_t)Nn * 4, stream);
    initsrc_kernel<<<(E2P / 4 + 255) / 256, 256, 0, stream>>>(srcx, E2P / 4);

    convw_kernel<<<(F_IN * F_HID + 255) / 256, 256, 0, stream>>>(W1, w1t, F_IN, F_HID);
    convw_kernel<<<(F_HID * F_OUT + 255) / 256, 256, 0, stream>>>(W2, w2t, F_HID, F_OUT);

    // CSR build
    count_kernel<<<(E / 4 + 255) / 256, 256, 0, stream>>>(colp, E, Nn, cnt);
    scan_partial_kernel<<<SCAN_B, 256, 0, stream>>>(cnt, bsum, Nn);
    scan_bsum_kernel<<<1, 256, 0, stream>>>(bsum, bofs, offs, Nn, SCAN_B);
    scan_fill_kernel<<<SCAN_B, 256, 0, stream>>>(cnt, bofs, offs, dinv, Nn);
    fill_kernel<<<((E + Nn) / 4 + 255) / 256, 256, 0, stream>>>(
        rowp, colp, E, Nn, offs, fil, srcx);

    // layer 1 (double-buffered global_load_lds GEMM, 782 blocks)
    gemm1_kernel<<<N_PAD / 64, 256, 0, stream>>>(x, w1t, dinv, h1);
    agg_kernel<F_HID, 4, true, true><<<N_PAD / 4, 256, 0, stream>>>(
        h1, offs, srcx, dinv, b1, h2, nullptr, Nn, N_PAD);

    // layer 2 (BM=64 -> 782 blocks)
    gemm_kernel<4, 1, 1, 4><<<dim3(N_PAD / 64, 1), 256, 0, stream>>>(
        h2, w2t, dinv, t2, F_HID, F_OUT);
    agg_kernel<F_OUT, 1, false, false><<<(Nn + 3) / 4, 256, 0, stream>>>(
        t2, offs, srcx, dinv, b2, nullptr, (float*)d_out, Nn, Nn);
}

// Round 12
// 381.319 us; speedup vs baseline: 1.0015x; 1.0015x over previous
//
#include <hip/hip_runtime.h>

// ---------------------------------------------------------------------------
// GCN 2-layer forward on MI355X.
//   h1s = dinv * (X @ W1)            (global_load_lds GEMM, counted-vmcnt dbuf)
//   h2  = relu(dinv * sum h1s + b1)  (CSR gather, 8-deep pipelined, bf16)
//   t2s = dinv * (h2 @ W2)           (bf16 MFMA GEMM + norm epilogue)
//   out = dinv * sum t2s + b2        (CSR gather, fp32 out)
// R12: gemm1 v6 — R11's dbuf was a no-op because __syncthreads() lowers to
// s_waitcnt vmcnt(0)+s_barrier, draining the prefetch every iteration
// (m99/m100 failure mode). Now: raw s_barrier + s_waitcnt vmcnt(6) — the 6
// newest global_load_lds stay in flight ACROSS the barriers (T4 recipe);
// only the final iteration drains to 0.
// ---------------------------------------------------------------------------

typedef __bf16 bf16x8 __attribute__((ext_vector_type(8)));
typedef __bf16 bf16x4 __attribute__((ext_vector_type(4)));
typedef float  f32x4  __attribute__((ext_vector_type(4)));

#define N_NODES  50000
#define N_PAD    50048   // 782 * 64
#define ZERO_ROW 50000   // first pad row: always all-zero in h1s/h2/t2s
#define F_IN     512
#define F_HID    256
#define F_OUT    64
#define SCAN_B   196     // ceil(50000 / 256)

#define GLOAD_LDS16(gp, lp) __builtin_amdgcn_global_load_lds(               \
    (const __attribute__((address_space(1))) void*)(gp),                    \
    (__attribute__((address_space(3))) void*)(lp), 16, 0, 0)

// ---------------------------------------------------------------------------
// W [K][N] f32 -> WT [N][K] bf16
__global__ __launch_bounds__(256) void convw_kernel(
    const float* __restrict__ W, __bf16* __restrict__ WT, int K, int N)
{
    int i = blockIdx.x * blockDim.x + threadIdx.x;
    if (i >= N * K) return;
    int n = i / K, k = i - n * K;
    WT[i] = (__bf16)W[(size_t)k * N + n];
}

// srcidx init: every slot points at the zero row (pad slots keep this)
__global__ __launch_bounds__(256) void initsrc_kernel(
    int* __restrict__ srcidx, int n4)
{
    int i = blockIdx.x * blockDim.x + threadIdx.x;
    if (i < n4) {
        int4 v = make_int4(ZERO_ROW, ZERO_ROW, ZERO_ROW, ZERO_ROW);
        *(int4*)(srcidx + i * 4) = v;
    }
}

// ---------------------------------------------------------------------------
// CSR build: histogram (4 edges/thread), scan of %8-padded caps, sort fill
__global__ __launch_bounds__(256) void count_kernel(
    const int* __restrict__ col, int E, int Nn, int* __restrict__ cnt)
{
    int e0 = (blockIdx.x * blockDim.x + threadIdx.x) * 4;
    if (e0 >= E) return;                 // E % 4 == 0
    int4 cc = *(const int4*)(col + e0);
    if ((unsigned)cc.x < (unsigned)Nn) atomicAdd(&cnt[cc.x], 1);
    if ((unsigned)cc.y < (unsigned)Nn) atomicAdd(&cnt[cc.y], 1);
    if ((unsigned)cc.z < (unsigned)Nn) atomicAdd(&cnt[cc.z], 1);
    if ((unsigned)cc.w < (unsigned)Nn) atomicAdd(&cnt[cc.w], 1);
}

__global__ __launch_bounds__(256) void scan_partial_kernel(
    const int* __restrict__ cnt, int* __restrict__ bsum, int N)
{
    __shared__ int s[256];
    const int t = threadIdx.x;
    const int i = blockIdx.x * 256 + t;
    int v = (i < N) ? ((cnt[i] + 1 + 7) & ~7) : 0;
    s[t] = v;
    __syncthreads();
    #pragma unroll
    for (int off = 128; off > 0; off >>= 1) {
        if (t < off) s[t] += s[t + off];
        __syncthreads();
    }
    if (t == 0) bsum[blockIdx.x] = s[0];
}

__global__ __launch_bounds__(256) void scan_bsum_kernel(
    const int* __restrict__ bsum, int* __restrict__ bofs,
    int* __restrict__ offs, int N, int PB)
{
    __shared__ int s[256];
    const int t = threadIdx.x;
    int v = (t < PB) ? bsum[t] : 0;
    s[t] = v;
    __syncthreads();
    #pragma unroll
    for (int off = 1; off < 256; off <<= 1) {
        int u = (t >= off) ? s[t - off] : 0;
        __syncthreads();
        s[t] += u;
        __syncthreads();
    }
    if (t < PB) bofs[t] = s[t] - v;
    if (t == 255) offs[N] = s[255];
}

__global__ __launch_bounds__(256) void scan_fill_kernel(
    const int* __restrict__ cnt, const int* __restrict__ bofs,
    int* __restrict__ offs, float* __restrict__ dinv, int N)
{
    __shared__ int s[256];
    const int t = threadIdx.x;
    const int i = blockIdx.x * 256 + t;
    int c   = (i < N) ? cnt[i] + 1 : 0;
    int cap = (c + 7) & ~7;
    s[t] = cap;
    __syncthreads();
    #pragma unroll
    for (int off = 1; off < 256; off <<= 1) {
        int u = (t >= off) ? s[t - off] : 0;
        __syncthreads();
        s[t] += u;
        __syncthreads();
    }
    if (i < N) {
        offs[i] = bofs[blockIdx.x] + s[t] - cap;
        dinv[i] = rsqrtf((float)c);
    }
}

__global__ __launch_bounds__(256) void fill_kernel(
    const int* __restrict__ row, const int* __restrict__ col,
    int E, int Nn, const int* __restrict__ offs,
    int* __restrict__ fill, int* __restrict__ srcidx)
{
    int e0 = (blockIdx.x * blockDim.x + threadIdx.x) * 4;
    int total = E + Nn;
    if (e0 >= total) return;
    int rr[4], cc[4];
    #pragma unroll
    for (int j = 0; j < 4; ++j) {
        int e = e0 + j;
        if (e < E)      { cc[j] = col[e]; rr[j] = row[e]; }
        else            { int i = e - E; cc[j] = (i < Nn) ? i : -1; rr[j] = cc[j]; }
    }
    #pragma unroll
    for (int j = 0; j < 4; ++j) {
        int c = cc[j], r = rr[j];
        if ((unsigned)c < (unsigned)Nn && (unsigned)r < (unsigned)Nn) {
            int p = offs[c] + atomicAdd(&fill[c], 1);
            srcidx[p] = r;
        }
    }
}

// ---------------------------------------------------------------------------
// GEMM1 v6: C[50048][256] = dinv[r] * (cvt_bf16(Xf32)[50048][512] @ W1T^T)
// BM=64, BN=256, BK=32, 4 waves (2x2), 16x16x32 MFMA, dbuf LDS.
// Per iter: STAGE(k+1, 6 gload_lds/thread) -> s_waitcnt vmcnt(6) (retire
// stage k, keep stage k+1 in flight) -> s_barrier -> compute buf[cur]
// -> s_barrier (WAR fence, NO vmcnt drain). Last iter drains vmcnt(0).
// Per-buffer layout: A fp32 [64][32] @0 (8KB), B bf16 [256][32] @8192 (16KB).
// XOR swizzle both sides: A chunk16 c'=c^(row&7); B chunk16 c'=c^((row>>1)&3).
__global__ __launch_bounds__(256, 3) void gemm1_kernel(
    const float* __restrict__ A, const __bf16* __restrict__ BT,
    const float* __restrict__ dinv, __bf16* __restrict__ C)
{
    __shared__ __align__(16) unsigned char lds[2][24576];

    const int tid  = threadIdx.x;
    const int lane = tid & 63;
    const int wv   = tid >> 6;
    const int wm = wv >> 1, wn = wv & 1;
    const int bm = blockIdx.x * 64;
    const int lr = lane & 15, kg = lane >> 4;

    // staging geometry (per-wave segments, lane l covers 16B)
    const int cA = (lane & 7) ^ (lane >> 3);          // A: row&7 == l>>3
    const int cB = (lane & 3) ^ ((lane >> 3) & 3);    // B: (row>>1)&3

    const float* gA[2]; int aoff[2];
    #pragma unroll
    for (int q = 0; q < 2; ++q) {
        int s   = wv * 2 + q;
        int row = s * 8 + (lane >> 3);
        int gr  = bm + row;
        if (gr >= N_NODES) gr = 0;       // clamp; pad C rows zeroed by dinv=0
        gA[q]   = A + (size_t)gr * F_IN + cA * 4;
        aoff[q] = s * 1024;
    }
    const __bf16* gB[4]; int boff[4];
    #pragma unroll
    for (int q = 0; q < 4; ++q) {
        int s   = wv * 4 + q;
        int row = s * 16 + (lane >> 2);
        gB[q]   = BT + (size_t)row * F_IN + cB * 8;
        boff[q] = 8192 + s * 1024;
    }

#define STAGE(b, kc) {                                                      \
        _Pragma("unroll")                                                   \
        for (int q = 0; q < 2; ++q)                                         \
            GLOAD_LDS16(gA[q] + (kc) * 32, &lds[b][aoff[q]]);               \
        _Pragma("unroll")                                                   \
        for (int q = 0; q < 4; ++q)                                         \
            GLOAD_LDS16(gB[q] + (kc) * 32, &lds[b][boff[q]]); }

    f32x4 acc[2][8] = {};

    STAGE(0, 0)            // 6 loads in flight

    #pragma unroll
    for (int kc = 0; kc < 16; ++kc) {
        const int cur = kc & 1;
        if (kc < 15) {
            STAGE(cur ^ 1, kc + 1)   // +6 newest
            // retire stage(kc) (oldest 6); keep stage(kc+1) in flight
            asm volatile("s_waitcnt vmcnt(6)" ::: "memory");
        } else {
            asm volatile("s_waitcnt vmcnt(0)" ::: "memory");
        }
        __builtin_amdgcn_sched_barrier(0);
        __builtin_amdgcn_s_barrier();        // all waves' stage(kc) landed
        __builtin_amdgcn_sched_barrier(0);

        const unsigned char* lb = lds[cur];
        bf16x8 af[2];
        #pragma unroll
        for (int m = 0; m < 2; ++m) {
            int ar = wm * 32 + m * 16 + lr;
            int h0 = ((kg << 1)    ) ^ (ar & 7);
            int h1 = ((kg << 1) | 1) ^ (ar & 7);
            float4 x0 = *(const float4*)(lb + (ar << 7) + (h0 << 4));
            float4 x1 = *(const float4*)(lb + (ar << 7) + (h1 << 4));
            af[m][0]=(__bf16)x0.x; af[m][1]=(__bf16)x0.y;
            af[m][2]=(__bf16)x0.z; af[m][3]=(__bf16)x0.w;
            af[m][4]=(__bf16)x1.x; af[m][5]=(__bf16)x1.y;
            af[m][6]=(__bf16)x1.z; af[m][7]=(__bf16)x1.w;
        }
        #pragma unroll
        for (int n = 0; n < 8; ++n) {
            int br = wn * 128 + n * 16 + lr;
            int ph = kg ^ ((br >> 1) & 3);
            bf16x8 bf = *(const bf16x8*)(lb + 8192 + (br << 6) + (ph << 4));
            #pragma unroll
            for (int m = 0; m < 2; ++m)
                acc[m][n] = __builtin_amdgcn_mfma_f32_16x16x32_bf16(
                    af[m], bf, acc[m][n], 0, 0, 0);
        }
        __builtin_amdgcn_sched_barrier(0);
        __builtin_amdgcn_s_barrier();        // WAR fence (no vmcnt drain!)
        __builtin_amdgcn_sched_barrier(0);
    }
#undef STAGE

    const int crow0 = bm + wm * 32 + kg * 4;
    const int ccol0 = wn * 128 + lr;
    #pragma unroll
    for (int m = 0; m < 2; ++m) {
        #pragma unroll
        for (int j = 0; j < 4; ++j) {
            int r = crow0 + m * 16 + j;
            float dv = (r < N_NODES) ? dinv[r] : 0.f;
            #pragma unroll
            for (int n = 0; n < 8; ++n)
                C[(size_t)r * F_HID + (ccol0 + n * 16)] = (__bf16)(dv * acc[m][n][j]);
        }
    }
}

// ---------------------------------------------------------------------------
// GEMM2: C[Mpad][N] = dinv[r] * (A[Mpad][K] @ BT[N][K]^T)
template<int WGM, int WGN, int FM, int FN>
__global__ __launch_bounds__(256) void gemm_kernel(
    const __bf16* __restrict__ A, const __bf16* __restrict__ BT,
    const float* __restrict__ dinv, __bf16* __restrict__ C, int K, int N)
{
    constexpr int BM = WGM * FM * 16;
    constexpr int BN = WGN * FN * 16;
    constexpr int BK = 32;
    constexpr int LDT = BK + 8;
    __shared__ __bf16 As[BM * LDT];
    __shared__ __bf16 Bs[BN * LDT];

    const int tid  = threadIdx.x;
    const int lane = tid & 63;
    const int wid  = tid >> 6;
    const int wm = wid / WGN, wn = wid % WGN;
    const int bm = blockIdx.x * BM;
    const int bn = blockIdx.y * BN;
    const int lr = lane & 15, kg = lane >> 4;

    const int arow = tid >> 2;
    const int achk = (tid & 3) * 8;

    f32x4 acc[FM][FN] = {};

    for (int k0 = 0; k0 < K; k0 += BK) {
        bf16x8 ra[BM / 64], rb[BN / 64];
        #pragma unroll
        for (int p = 0; p < BM / 64; ++p)
            ra[p] = *(const bf16x8*)(A + (size_t)(bm + p * 64 + arow) * K + k0 + achk);
        #pragma unroll
        for (int p = 0; p < BN / 64; ++p)
            rb[p] = *(const bf16x8*)(BT + (size_t)(bn + p * 64 + arow) * K + k0 + achk);
        __syncthreads();
        #pragma unroll
        for (int p = 0; p < BM / 64; ++p)
            *(bf16x8*)(As + (p * 64 + arow) * LDT + achk) = ra[p];
        #pragma unroll
        for (int p = 0; p < BN / 64; ++p)
            *(bf16x8*)(Bs + (p * 64 + arow) * LDT + achk) = rb[p];
        __syncthreads();

        bf16x8 af[FM], bfv[FN];
        #pragma unroll
        for (int m = 0; m < FM; ++m)
            af[m] = *(const bf16x8*)(As + (wm * FM * 16 + m * 16 + lr) * LDT + kg * 8);
        #pragma unroll
        for (int n = 0; n < FN; ++n)
            bfv[n] = *(const bf16x8*)(Bs + (wn * FN * 16 + n * 16 + lr) * LDT + kg * 8);
        #pragma unroll
        for (int m = 0; m < FM; ++m)
            #pragma unroll
            for (int n = 0; n < FN; ++n)
                acc[m][n] = __builtin_amdgcn_mfma_f32_16x16x32_bf16(
                    af[m], bfv[n], acc[m][n], 0, 0, 0);
    }

    const int crow0 = bm + wm * FM * 16 + kg * 4;
    const int ccol0 = bn + wn * FN * 16 + lr;
    #pragma unroll
    for (int m = 0; m < FM; ++m) {
        #pragma unroll
        for (int j = 0; j < 4; ++j) {
            int r = crow0 + m * 16 + j;
            float dv = (r < N_NODES) ? dinv[r] : 0.f;
            #pragma unroll
            for (int n = 0; n < FN; ++n)
                C[(size_t)r * N + (ccol0 + n * 16)] = (__bf16)(dv * acc[m][n][j]);
        }
    }
}

// ---------------------------------------------------------------------------
// CSR aggregation, 8-deep: out[n][f] = dinv[n]*sum_e Hs[src[e]][f] + bias[f]
template<int F, int FP, bool RELU, bool BF16OUT>
__global__ __launch_bounds__(256) void agg_kernel(
    const __bf16* __restrict__ H,
    const int* __restrict__ offs, const int* __restrict__ srcidx,
    const float* __restrict__ dinv, const float* __restrict__ bias,
    __bf16* __restrict__ outb, float* __restrict__ outf,
    int Nn, int Mpad)
{
    const int lane = threadIdx.x & 63;
    const int node = blockIdx.x * 4 + (threadIdx.x >> 6);
    if (node >= Mpad) return;
    if (node >= Nn) {
        if (BF16OUT) {
            #pragma unroll
            for (int j = 0; j < FP; ++j)
                outb[(size_t)node * F + lane * FP + j] = (__bf16)0.f;
        }
        return;
    }
    const int e0 = offs[node], e1 = offs[node + 1];   // both %8 == 0
    const float dv = dinv[node];
    float acc[FP] = {};
    for (int e = e0; e < e1; e += 8) {
        int4 sa = *(const int4*)(srcidx + e);
        int4 sb = *(const int4*)(srcidx + e + 4);
        if constexpr (FP == 4) {
            bf16x4 v0 = *(const bf16x4*)(H + (size_t)sa.x * F + lane * 4);
            bf16x4 v1 = *(const bf16x4*)(H + (size_t)sa.y * F + lane * 4);
            bf16x4 v2 = *(const bf16x4*)(H + (size_t)sa.z * F + lane * 4);
            bf16x4 v3 = *(const bf16x4*)(H + (size_t)sa.w * F + lane * 4);
            bf16x4 v4 = *(const bf16x4*)(H + (size_t)sb.x * F + lane * 4);
            bf16x4 v5 = *(const bf16x4*)(H + (size_t)sb.y * F + lane * 4);
            bf16x4 v6 = *(const bf16x4*)(H + (size_t)sb.z * F + lane * 4);
            bf16x4 v7 = *(const bf16x4*)(H + (size_t)sb.w * F + lane * 4);
            #pragma unroll
            for (int j = 0; j < 4; ++j)
                acc[j] += ((float)v0[j] + (float)v1[j] + (float)v2[j] + (float)v3[j])
                        + ((float)v4[j] + (float)v5[j] + (float)v6[j] + (float)v7[j]);
        } else {
            __bf16 v0 = H[(size_t)sa.x * F + lane];
            __bf16 v1 = H[(size_t)sa.y * F + lane];
            __bf16 v2 = H[(size_t)sa.z * F + lane];
            __bf16 v3 = H[(size_t)sa.w * F + lane];
            __bf16 v4 = H[(size_t)sb.x * F + lane];
            __bf16 v5 = H[(size_t)sb.y * F + lane];
            __bf16 v6 = H[(size_t)sb.z * F + lane];
            __bf16 v7 = H[(size_t)sb.w * F + lane];
            acc[0] += ((float)v0 + (float)v1 + (float)v2 + (float)v3)
                    + ((float)v4 + (float)v5 + (float)v6 + (float)v7);
        }
    }
    if constexpr (BF16OUT) {
        bf16x4 ov;
        #pragma unroll
        for (int j = 0; j < FP; ++j) {
            float r = dv * acc[j] + bias[lane * FP + j];
            if (RELU) r = fmaxf(r, 0.f);
            if constexpr (FP == 4) ov[j] = (__bf16)r;
            else outb[(size_t)node * F + lane] = (__bf16)r;
        }
        if constexpr (FP == 4)
            *(bf16x4*)(outb + (size_t)node * F + lane * 4) = ov;
    } else {
        #pragma unroll
        for (int j = 0; j < FP; ++j) {
            float r = dv * acc[j] + bias[lane * FP + j];
            if (RELU) r = fmaxf(r, 0.f);
            outf[(size_t)node * F + lane * FP + j] = r;
        }
    }
}

// ---------------------------------------------------------------------------
extern "C" void kernel_launch(void* const* d_in, const int* in_sizes, int n_in,
                              void* d_out, int out_size, void* d_ws, size_t ws_size,
                              hipStream_t stream)
{
    const float* x   = (const float*)d_in[0];
    const int*   ei  = (const int*)d_in[1];
    const float* W1  = (const float*)d_in[2];
    const float* b1  = (const float*)d_in[3];
    const float* W2  = (const float*)d_in[4];
    const float* b2  = (const float*)d_in[5];
    const int E  = in_sizes[1] / 2;
    const int Nn = N_NODES;
    const int E2P = E + 8 * Nn;            // %8-padded CSR capacity upper bound
    const int* rowp = ei;
    const int* colp = ei + E;

    char* w = (char*)d_ws;
    auto alloc = [&](size_t bytes) {
        char* p = w; w += (bytes + 255) & ~(size_t)255; return p;
    };
    __bf16* h1   = (__bf16*)alloc((size_t)N_PAD * F_HID * 2);  // reused as t2
    __bf16* h2   = (__bf16*)alloc((size_t)N_PAD * F_HID * 2);
    __bf16* w1t  = (__bf16*)alloc((size_t)F_HID * F_IN  * 2);
    __bf16* w2t  = (__bf16*)alloc((size_t)F_OUT * F_HID * 2);
    int*    cnt  = (int*)  alloc((size_t)Nn * 4);
    int*    fil  = (int*)  alloc((size_t)Nn * 4);
    int*    offs = (int*)  alloc((size_t)(Nn + 1) * 4);
    float*  dinv = (float*)alloc((size_t)Nn * 4);
    int*    bsum = (int*)  alloc((size_t)SCAN_B * 4);
    int*    bofs = (int*)  alloc((size_t)SCAN_B * 4);
    int*    srcx = (int*)  alloc((size_t)E2P * 4);
    __bf16* t2 = h1;    // h1 dead after agg1

    hipMemsetAsync(cnt, 0, (size_t)Nn * 4, stream);
    hipMemsetAsync(fil, 0, (size_t)Nn * 4, stream);
    initsrc_kernel<<<(E2P / 4 + 255) / 256, 256, 0, stream>>>(srcx, E2P / 4);

    convw_kernel<<<(F_IN * F_HID + 255) / 256, 256, 0, stream>>>(W1, w1t, F_IN, F_HID);
    convw_kernel<<<(F_HID * F_OUT + 255) / 256, 256, 0, stream>>>(W2, w2t, F_HID, F_OUT);

    // CSR build
    count_kernel<<<(E / 4 + 255) / 256, 256, 0, stream>>>(colp, E, Nn, cnt);
    scan_partial_kernel<<<SCAN_B, 256, 0, stream>>>(cnt, bsum, Nn);
    scan_bsum_kernel<<<1, 256, 0, stream>>>(bsum, bofs, offs, Nn, SCAN_B);
    scan_fill_kernel<<<SCAN_B, 256, 0, stream>>>(cnt, bofs, offs, dinv, Nn);
    fill_kernel<<<((E + Nn) / 4 + 255) / 256, 256, 0, stream>>>(
        rowp, colp, E, Nn, offs, fil, srcx);

    // layer 1 (counted-vmcnt dbuf global_load_lds GEMM, 782 blocks)
    gemm1_kernel<<<N_PAD / 64, 256, 0, stream>>>(x, w1t, dinv, h1);
    agg_kernel<F_HID, 4, true, true><<<N_PAD / 4, 256, 0, stream>>>(
        h1, offs, srcx, dinv, b1, h2, nullptr, Nn, N_PAD);

    // layer 2 (BM=64 -> 782 blocks)
    gemm_kernel<4, 1, 1, 4><<<dim3(N_PAD / 64, 1), 256, 0, stream>>>(
        h2, w2t, dinv, t2, F_HID, F_OUT);
    agg_kernel<F_OUT, 1, false, false><<<(Nn + 3) / 4, 256, 0, stream>>>(
        t2, offs, srcx, dinv, b2, nullptr, (float*)d_out, Nn, Nn);
}

// Round 13
// 372.916 us; speedup vs baseline: 1.0241x; 1.0225x over previous
//
#include <hip/hip_runtime.h>

// ---------------------------------------------------------------------------
// GCN 2-layer forward on MI355X.
//   h1s = dinv * (X @ W1)            (global_load_lds GEMM, counted-vmcnt dbuf)
//   h2  = relu(dinv * sum h1s + b1)  (CSR gather, 8-deep pipelined, bf16)
//   t2s = dinv * (h2 @ W2)           (bf16 MFMA GEMM + norm epilogue)
//   out = dinv * sum t2s + b2        (CSR gather, fp32 out)
// R13: srcidx int32 -> uint16 (50000 < 65536). R12 profile: fill_kernel 67us
// with 56.5MB WRITE_SIZE vs 3.4MB logical = full-line write-allocate on every
// random 4B scatter. uint16 halves the scatter region and line traffic.
// ---------------------------------------------------------------------------

typedef __bf16 bf16x8 __attribute__((ext_vector_type(8)));
typedef __bf16 bf16x4 __attribute__((ext_vector_type(4)));
typedef float  f32x4  __attribute__((ext_vector_type(4)));
typedef unsigned short u16x8 __attribute__((ext_vector_type(8)));

#define N_NODES  50000
#define N_PAD    50048   // 782 * 64
#define ZERO_ROW 50000   // first pad row: always all-zero in h1s/h2/t2s
#define F_IN     512
#define F_HID    256
#define F_OUT    64
#define SCAN_B   196     // ceil(50000 / 256)

#define GLOAD_LDS16(gp, lp) __builtin_amdgcn_global_load_lds(               \
    (const __attribute__((address_space(1))) void*)(gp),                    \
    (__attribute__((address_space(3))) void*)(lp), 16, 0, 0)

// ---------------------------------------------------------------------------
// W [K][N] f32 -> WT [N][K] bf16
__global__ __launch_bounds__(256) void convw_kernel(
    const float* __restrict__ W, __bf16* __restrict__ WT, int K, int N)
{
    int i = blockIdx.x * blockDim.x + threadIdx.x;
    if (i >= N * K) return;
    int n = i / K, k = i - n * K;
    WT[i] = (__bf16)W[(size_t)k * N + n];
}

// srcidx init: every slot points at the zero row (pad slots keep this)
__global__ __launch_bounds__(256) void initsrc_kernel(
    unsigned short* __restrict__ srcidx, int n8)
{
    int i = blockIdx.x * blockDim.x + threadIdx.x;
    if (i < n8) {
        u16x8 v = { ZERO_ROW, ZERO_ROW, ZERO_ROW, ZERO_ROW,
                    ZERO_ROW, ZERO_ROW, ZERO_ROW, ZERO_ROW };
        *(u16x8*)(srcidx + i * 8) = v;
    }
}

// ---------------------------------------------------------------------------
// CSR build: histogram (4 edges/thread), scan of %8-padded caps, sort fill
__global__ __launch_bounds__(256) void count_kernel(
    const int* __restrict__ col, int E, int Nn, int* __restrict__ cnt)
{
    int e0 = (blockIdx.x * blockDim.x + threadIdx.x) * 4;
    if (e0 >= E) return;                 // E % 4 == 0
    int4 cc = *(const int4*)(col + e0);
    if ((unsigned)cc.x < (unsigned)Nn) atomicAdd(&cnt[cc.x], 1);
    if ((unsigned)cc.y < (unsigned)Nn) atomicAdd(&cnt[cc.y], 1);
    if ((unsigned)cc.z < (unsigned)Nn) atomicAdd(&cnt[cc.z], 1);
    if ((unsigned)cc.w < (unsigned)Nn) atomicAdd(&cnt[cc.w], 1);
}

__global__ __launch_bounds__(256) void scan_partial_kernel(
    const int* __restrict__ cnt, int* __restrict__ bsum, int N)
{
    __shared__ int s[256];
    const int t = threadIdx.x;
    const int i = blockIdx.x * 256 + t;
    int v = (i < N) ? ((cnt[i] + 1 + 7) & ~7) : 0;
    s[t] = v;
    __syncthreads();
    #pragma unroll
    for (int off = 128; off > 0; off >>= 1) {
        if (t < off) s[t] += s[t + off];
        __syncthreads();
    }
    if (t == 0) bsum[blockIdx.x] = s[0];
}

__global__ __launch_bounds__(256) void scan_bsum_kernel(
    const int* __restrict__ bsum, int* __restrict__ bofs,
    int* __restrict__ offs, int N, int PB)
{
    __shared__ int s[256];
    const int t = threadIdx.x;
    int v = (t < PB) ? bsum[t] : 0;
    s[t] = v;
    __syncthreads();
    #pragma unroll
    for (int off = 1; off < 256; off <<= 1) {
        int u = (t >= off) ? s[t - off] : 0;
        __syncthreads();
        s[t] += u;
        __syncthreads();
    }
    if (t < PB) bofs[t] = s[t] - v;
    if (t == 255) offs[N] = s[255];
}

__global__ __launch_bounds__(256) void scan_fill_kernel(
    const int* __restrict__ cnt, const int* __restrict__ bofs,
    int* __restrict__ offs, float* __restrict__ dinv, int N)
{
    __shared__ int s[256];
    const int t = threadIdx.x;
    const int i = blockIdx.x * 256 + t;
    int c   = (i < N) ? cnt[i] + 1 : 0;
    int cap = (c + 7) & ~7;
    s[t] = cap;
    __syncthreads();
    #pragma unroll
    for (int off = 1; off < 256; off <<= 1) {
        int u = (t >= off) ? s[t - off] : 0;
        __syncthreads();
        s[t] += u;
        __syncthreads();
    }
    if (i < N) {
        offs[i] = bofs[blockIdx.x] + s[t] - cap;
        dinv[i] = rsqrtf((float)c);
    }
}

__global__ __launch_bounds__(256) void fill_kernel(
    const int* __restrict__ row, const int* __restrict__ col,
    int E, int Nn, const int* __restrict__ offs,
    int* __restrict__ fill, unsigned short* __restrict__ srcidx)
{
    int e0 = (blockIdx.x * blockDim.x + threadIdx.x) * 4;
    int total = E + Nn;
    if (e0 >= total) return;
    int rr[4], cc[4];
    #pragma unroll
    for (int j = 0; j < 4; ++j) {
        int e = e0 + j;
        if (e < E)      { cc[j] = col[e]; rr[j] = row[e]; }
        else            { int i = e - E; cc[j] = (i < Nn) ? i : -1; rr[j] = cc[j]; }
    }
    #pragma unroll
    for (int j = 0; j < 4; ++j) {
        int c = cc[j], r = rr[j];
        if ((unsigned)c < (unsigned)Nn && (unsigned)r < (unsigned)Nn) {
            int p = offs[c] + atomicAdd(&fill[c], 1);
            srcidx[p] = (unsigned short)r;
        }
    }
}

// ---------------------------------------------------------------------------
// GEMM1 v6 (unchanged from R12): C = dinv[r] * (cvt_bf16(X) @ W1T^T)
// BM=64, BN=256, BK=32, 4 waves, dbuf LDS + global_load_lds + counted vmcnt.
__global__ __launch_bounds__(256, 3) void gemm1_kernel(
    const float* __restrict__ A, const __bf16* __restrict__ BT,
    const float* __restrict__ dinv, __bf16* __restrict__ C)
{
    __shared__ __align__(16) unsigned char lds[2][24576];

    const int tid  = threadIdx.x;
    const int lane = tid & 63;
    const int wv   = tid >> 6;
    const int wm = wv >> 1, wn = wv & 1;
    const int bm = blockIdx.x * 64;
    const int lr = lane & 15, kg = lane >> 4;

    const int cA = (lane & 7) ^ (lane >> 3);          // A: row&7 == l>>3
    const int cB = (lane & 3) ^ ((lane >> 3) & 3);    // B: (row>>1)&3

    const float* gA[2]; int aoff[2];
    #pragma unroll
    for (int q = 0; q < 2; ++q) {
        int s   = wv * 2 + q;
        int row = s * 8 + (lane >> 3);
        int gr  = bm + row;
        if (gr >= N_NODES) gr = 0;       // clamp; pad C rows zeroed by dinv=0
        gA[q]   = A + (size_t)gr * F_IN + cA * 4;
        aoff[q] = s * 1024;
    }
    const __bf16* gB[4]; int boff[4];
    #pragma unroll
    for (int q = 0; q < 4; ++q) {
        int s   = wv * 4 + q;
        int row = s * 16 + (lane >> 2);
        gB[q]   = BT + (size_t)row * F_IN + cB * 8;
        boff[q] = 8192 + s * 1024;
    }

#define STAGE(b, kc) {                                                      \
        _Pragma("unroll")                                                   \
        for (int q = 0; q < 2; ++q)                                         \
            GLOAD_LDS16(gA[q] + (kc) * 32, &lds[b][aoff[q]]);               \
        _Pragma("unroll")                                                   \
        for (int q = 0; q < 4; ++q)                                         \
            GLOAD_LDS16(gB[q] + (kc) * 32, &lds[b][boff[q]]); }

    f32x4 acc[2][8] = {};

    STAGE(0, 0)

    #pragma unroll
    for (int kc = 0; kc < 16; ++kc) {
        const int cur = kc & 1;
        if (kc < 15) {
            STAGE(cur ^ 1, kc + 1)
            asm volatile("s_waitcnt vmcnt(6)" ::: "memory");
        } else {
            asm volatile("s_waitcnt vmcnt(0)" ::: "memory");
        }
        __builtin_amdgcn_sched_barrier(0);
        __builtin_amdgcn_s_barrier();
        __builtin_amdgcn_sched_barrier(0);

        const unsigned char* lb = lds[cur];
        bf16x8 af[2];
        #pragma unroll
        for (int m = 0; m < 2; ++m) {
            int ar = wm * 32 + m * 16 + lr;
            int h0 = ((kg << 1)    ) ^ (ar & 7);
            int h1 = ((kg << 1) | 1) ^ (ar & 7);
            float4 x0 = *(const float4*)(lb + (ar << 7) + (h0 << 4));
            float4 x1 = *(const float4*)(lb + (ar << 7) + (h1 << 4));
            af[m][0]=(__bf16)x0.x; af[m][1]=(__bf16)x0.y;
            af[m][2]=(__bf16)x0.z; af[m][3]=(__bf16)x0.w;
            af[m][4]=(__bf16)x1.x; af[m][5]=(__bf16)x1.y;
            af[m][6]=(__bf16)x1.z; af[m][7]=(__bf16)x1.w;
        }
        #pragma unroll
        for (int n = 0; n < 8; ++n) {
            int br = wn * 128 + n * 16 + lr;
            int ph = kg ^ ((br >> 1) & 3);
            bf16x8 bf = *(const bf16x8*)(lb + 8192 + (br << 6) + (ph << 4));
            #pragma unroll
            for (int m = 0; m < 2; ++m)
                acc[m][n] = __builtin_amdgcn_mfma_f32_16x16x32_bf16(
                    af[m], bf, acc[m][n], 0, 0, 0);
        }
        __builtin_amdgcn_sched_barrier(0);
        __builtin_amdgcn_s_barrier();        // WAR fence (no vmcnt drain)
        __builtin_amdgcn_sched_barrier(0);
    }
#undef STAGE

    const int crow0 = bm + wm * 32 + kg * 4;
    const int ccol0 = wn * 128 + lr;
    #pragma unroll
    for (int m = 0; m < 2; ++m) {
        #pragma unroll
        for (int j = 0; j < 4; ++j) {
            int r = crow0 + m * 16 + j;
            float dv = (r < N_NODES) ? dinv[r] : 0.f;
            #pragma unroll
            for (int n = 0; n < 8; ++n)
                C[(size_t)r * F_HID + (ccol0 + n * 16)] = (__bf16)(dv * acc[m][n][j]);
        }
    }
}

// ---------------------------------------------------------------------------
// GEMM2: C[Mpad][N] = dinv[r] * (A[Mpad][K] @ BT[N][K]^T)
template<int WGM, int WGN, int FM, int FN>
__global__ __launch_bounds__(256) void gemm_kernel(
    const __bf16* __restrict__ A, const __bf16* __restrict__ BT,
    const float* __restrict__ dinv, __bf16* __restrict__ C, int K, int N)
{
    constexpr int BM = WGM * FM * 16;
    constexpr int BN = WGN * FN * 16;
    constexpr int BK = 32;
    constexpr int LDT = BK + 8;
    __shared__ __bf16 As[BM * LDT];
    __shared__ __bf16 Bs[BN * LDT];

    const int tid  = threadIdx.x;
    const int lane = tid & 63;
    const int wid  = tid >> 6;
    const int wm = wid / WGN, wn = wid % WGN;
    const int bm = blockIdx.x * BM;
    const int bn = blockIdx.y * BN;
    const int lr = lane & 15, kg = lane >> 4;

    const int arow = tid >> 2;
    const int achk = (tid & 3) * 8;

    f32x4 acc[FM][FN] = {};

    for (int k0 = 0; k0 < K; k0 += BK) {
        bf16x8 ra[BM / 64], rb[BN / 64];
        #pragma unroll
        for (int p = 0; p < BM / 64; ++p)
            ra[p] = *(const bf16x8*)(A + (size_t)(bm + p * 64 + arow) * K + k0 + achk);
        #pragma unroll
        for (int p = 0; p < BN / 64; ++p)
            rb[p] = *(const bf16x8*)(BT + (size_t)(bn + p * 64 + arow) * K + k0 + achk);
        __syncthreads();
        #pragma unroll
        for (int p = 0; p < BM / 64; ++p)
            *(bf16x8*)(As + (p * 64 + arow) * LDT + achk) = ra[p];
        #pragma unroll
        for (int p = 0; p < BN / 64; ++p)
            *(bf16x8*)(Bs + (p * 64 + arow) * LDT + achk) = rb[p];
        __syncthreads();

        bf16x8 af[FM], bfv[FN];
        #pragma unroll
        for (int m = 0; m < FM; ++m)
            af[m] = *(const bf16x8*)(As + (wm * FM * 16 + m * 16 + lr) * LDT + kg * 8);
        #pragma unroll
        for (int n = 0; n < FN; ++n)
            bfv[n] = *(const bf16x8*)(Bs + (wn * FN * 16 + n * 16 + lr) * LDT + kg * 8);
        #pragma unroll
        for (int m = 0; m < FM; ++m)
            #pragma unroll
            for (int n = 0; n < FN; ++n)
                acc[m][n] = __builtin_amdgcn_mfma_f32_16x16x32_bf16(
                    af[m], bfv[n], acc[m][n], 0, 0, 0);
    }

    const int crow0 = bm + wm * FM * 16 + kg * 4;
    const int ccol0 = bn + wn * FN * 16 + lr;
    #pragma unroll
    for (int m = 0; m < FM; ++m) {
        #pragma unroll
        for (int j = 0; j < 4; ++j) {
            int r = crow0 + m * 16 + j;
            float dv = (r < N_NODES) ? dinv[r] : 0.f;
            #pragma unroll
            for (int n = 0; n < FN; ++n)
                C[(size_t)r * N + (ccol0 + n * 16)] = (__bf16)(dv * acc[m][n][j]);
        }
    }
}

// ---------------------------------------------------------------------------
// CSR aggregation, 8-deep, uint16 indices:
// out[n][f] = dinv[n]*sum_e Hs[src[e]][f] + bias[f]
template<int F, int FP, bool RELU, bool BF16OUT>
__global__ __launch_bounds__(256) void agg_kernel(
    const __bf16* __restrict__ H,
    const int* __restrict__ offs, const unsigned short* __restrict__ srcidx,
    const float* __restrict__ dinv, const float* __restrict__ bias,
    __bf16* __restrict__ outb, float* __restrict__ outf,
    int Nn, int Mpad)
{
    const int lane = threadIdx.x & 63;
    const int node = blockIdx.x * 4 + (threadIdx.x >> 6);
    if (node >= Mpad) return;
    if (node >= Nn) {
        if (BF16OUT) {
            #pragma unroll
            for (int j = 0; j < FP; ++j)
                outb[(size_t)node * F + lane * FP + j] = (__bf16)0.f;
        }
        return;
    }
    const int e0 = offs[node], e1 = offs[node + 1];   // both %8 == 0
    const float dv = dinv[node];
    float acc[FP] = {};
    for (int e = e0; e < e1; e += 8) {
        u16x8 ss = *(const u16x8*)(srcidx + e);       // 16B-aligned (e%8==0)
        if constexpr (FP == 4) {
            bf16x4 v0 = *(const bf16x4*)(H + (size_t)ss[0] * F + lane * 4);
            bf16x4 v1 = *(const bf16x4*)(H + (size_t)ss[1] * F + lane * 4);
            bf16x4 v2 = *(const bf16x4*)(H + (size_t)ss[2] * F + lane * 4);
            bf16x4 v3 = *(const bf16x4*)(H + (size_t)ss[3] * F + lane * 4);
            bf16x4 v4 = *(const bf16x4*)(H + (size_t)ss[4] * F + lane * 4);
            bf16x4 v5 = *(const bf16x4*)(H + (size_t)ss[5] * F + lane * 4);
            bf16x4 v6 = *(const bf16x4*)(H + (size_t)ss[6] * F + lane * 4);
            bf16x4 v7 = *(const bf16x4*)(H + (size_t)ss[7] * F + lane * 4);
            #pragma unroll
            for (int j = 0; j < 4; ++j)
                acc[j] += ((float)v0[j] + (float)v1[j] + (float)v2[j] + (float)v3[j])
                        + ((float)v4[j] + (float)v5[j] + (float)v6[j] + (float)v7[j]);
        } else {
            __bf16 v0 = H[(size_t)ss[0] * F + lane];
            __bf16 v1 = H[(size_t)ss[1] * F + lane];
            __bf16 v2 = H[(size_t)ss[2] * F + lane];
            __bf16 v3 = H[(size_t)ss[3] * F + lane];
            __bf16 v4 = H[(size_t)ss[4] * F + lane];
            __bf16 v5 = H[(size_t)ss[5] * F + lane];
            __bf16 v6 = H[(size_t)ss[6] * F + lane];
            __bf16 v7 = H[(size_t)ss[7] * F + lane];
            acc[0] += ((float)v0 + (float)v1 + (float)v2 + (float)v3)
                    + ((float)v4 + (float)v5 + (float)v6 + (float)v7);
        }
    }
    if constexpr (BF16OUT) {
        bf16x4 ov;
        #pragma unroll
        for (int j = 0; j < FP; ++j) {
            float r = dv * acc[j] + bias[lane * FP + j];
            if (RELU) r = fmaxf(r, 0.f);
            if constexpr (FP == 4) ov[j] = (__bf16)r;
            else outb[(size_t)node * F + lane] = (__bf16)r;
        }
        if constexpr (FP == 4)
            *(bf16x4*)(outb + (size_t)node * F + lane * 4) = ov;
    } else {
        #pragma unroll
        for (int j = 0; j < FP; ++j) {
            float r = dv * acc[j] + bias[lane * FP + j];
            if (RELU) r = fmaxf(r, 0.f);
            outf[(size_t)node * F + lane * FP + j] = r;
        }
    }
}

// ---------------------------------------------------------------------------
extern "C" void kernel_launch(void* const* d_in, const int* in_sizes, int n_in,
                              void* d_out, int out_size, void* d_ws, size_t ws_size,
                              hipStream_t stream)
{
    const float* x   = (const float*)d_in[0];
    const int*   ei  = (const int*)d_in[1];
    const float* W1  = (const float*)d_in[2];
    const float* b1  = (const float*)d_in[3];
    const float* W2  = (const float*)d_in[4];
    const float* b2  = (const float*)d_in[5];
    const int E  = in_sizes[1] / 2;
    const int Nn = N_NODES;
    const int E2P = (E + 8 * Nn + 7) & ~7;     // %8-padded CSR capacity bound
    const int* rowp = ei;
    const int* colp = ei + E;

    char* w = (char*)d_ws;
    auto alloc = [&](size_t bytes) {
        char* p = w; w += (bytes + 255) & ~(size_t)255; return p;
    };
    __bf16* h1   = (__bf16*)alloc((size_t)N_PAD * F_HID * 2);  // reused as t2
    __bf16* h2   = (__bf16*)alloc((size_t)N_PAD * F_HID * 2);
    __bf16* w1t  = (__bf16*)alloc((size_t)F_HID * F_IN  * 2);
    __bf16* w2t  = (__bf16*)alloc((size_t)F_OUT * F_HID * 2);
    int*    cnt  = (int*)  alloc((size_t)Nn * 4);
    int*    fil  = (int*)  alloc((size_t)Nn * 4);
    int*    offs = (int*)  alloc((size_t)(Nn + 1) * 4);
    float*  dinv = (float*)alloc((size_t)Nn * 4);
    int*    bsum = (int*)  alloc((size_t)SCAN_B * 4);
    int*    bofs = (int*)  alloc((size_t)SCAN_B * 4);
    unsigned short* srcx = (unsigned short*)alloc((size_t)E2P * 2);
    __bf16* t2 = h1;    // h1 dead after agg1

    hipMemsetAsync(cnt, 0, (size_t)Nn * 4, stream);
    hipMemsetAsync(fil, 0, (size_t)Nn * 4, stream);
    initsrc_kernel<<<(E2P / 8 + 255) / 256, 256, 0, stream>>>(srcx, E2P / 8);

    convw_kernel<<<(F_IN * F_HID + 255) / 256, 256, 0, stream>>>(W1, w1t, F_IN, F_HID);
    convw_kernel<<<(F_HID * F_OUT + 255) / 256, 256, 0, stream>>>(W2, w2t, F_HID, F_OUT);

    // CSR build
    count_kernel<<<(E / 4 + 255) / 256, 256, 0, stream>>>(colp, E, Nn, cnt);
    scan_partial_kernel<<<SCAN_B, 256, 0, stream>>>(cnt, bsum, Nn);
    scan_bsum_kernel<<<1, 256, 0, stream>>>(bsum, bofs, offs, Nn, SCAN_B);
    scan_fill_kernel<<<SCAN_B, 256, 0, stream>>>(cnt, bofs, offs, dinv, Nn);
    fill_kernel<<<((E + Nn) / 4 + 255) / 256, 256, 0, stream>>>(
        rowp, colp, E, Nn, offs, fil, srcx);

    // layer 1
    gemm1_kernel<<<N_PAD / 64, 256, 0, stream>>>(x, w1t, dinv, h1);
    agg_kernel<F_HID, 4, true, true><<<N_PAD / 4, 256, 0, stream>>>(
        h1, offs, srcx, dinv, b1, h2, nullptr, Nn, N_PAD);

    // layer 2
    gemm_kernel<4, 1, 1, 4><<<dim3(N_PAD / 64, 1), 256, 0, stream>>>(
        h2, w2t, dinv, t2, F_HID, F_OUT);
    agg_kernel<F_OUT, 1, false, false><<<(Nn + 3) / 4, 256, 0, stream>>>(
        t2, offs, srcx, dinv, b2, nullptr, (float*)d_out, Nn, Nn);
}